// Round 6
// baseline (440.224 us; speedup 1.0000x reference)
//
#include <hip/hip_runtime.h>
#include <hip/hip_bf16.h>
#include <math.h>

#define BATCH 32
#define C 256
#define HW 3136
#define OUTROW 32896
#define KSPLIT 7
#define KCHUNK 448   // HW / KSPLIT, multiple of 32

typedef __bf16 b8v __attribute__((ext_vector_type(8)));
typedef float  f4v __attribute__((ext_vector_type(4)));

__device__ __forceinline__ unsigned short f2bf(float f) {
    union { float f; unsigned u; } v; v.f = f;
    unsigned r = v.u + 0x7FFFu + ((v.u >> 16) & 1u);
    return (unsigned short)(r >> 16);
}
__device__ __forceinline__ float bf2f(unsigned short h) {
    union { unsigned u; float f; } v; v.u = ((unsigned)h) << 16; return v.f;
}
__device__ __forceinline__ void split2(float x, unsigned short& h, unsigned short& l) {
    h = f2bf(x);
    l = f2bf(x - bf2f(h));
}

__device__ __forceinline__ void stage16(const unsigned short* g, unsigned short* l) {
    __builtin_amdgcn_global_load_lds(
        (const __attribute__((address_space(1))) unsigned int*)g,
        (__attribute__((address_space(3))) unsigned int*)l,
        16, 0, 0);
}

__device__ __forceinline__ float wave_sum(float v) {
    for (int o = 32; o; o >>= 1) v += __shfl_down(v, o, 64);
    return v;
}

// ---------------------------------------------------------------------------
// prep: x -> hi/lo bf16 split, per-row sum and sum-of-squares
// ---------------------------------------------------------------------------
__global__ void k_prep(const float* __restrict__ x, unsigned short* __restrict__ xh,
                       unsigned short* __restrict__ xl, float* __restrict__ sbuf,
                       float* __restrict__ qbuf) {
    const int row = blockIdx.x;
    const float4* xr = (const float4*)(x + (size_t)row * HW);
    ushort4* hr = (ushort4*)(xh + (size_t)row * HW);
    ushort4* lr = (ushort4*)(xl + (size_t)row * HW);
    float s = 0.f, q = 0.f;
    for (int c = threadIdx.x; c < HW / 4; c += 256) {
        float4 v = xr[c];
        ushort4 h, l;
        split2(v.x, h.x, l.x); split2(v.y, h.y, l.y);
        split2(v.z, h.z, l.z); split2(v.w, h.w, l.w);
        hr[c] = h; lr[c] = l;
        s += v.x + v.y + v.z + v.w;
        q += v.x * v.x + v.y * v.y + v.z * v.z + v.w * v.w;
    }
    s = wave_sum(s); q = wave_sum(q);
    __shared__ float ss[4], qq[4];
    if ((threadIdx.x & 63) == 0) { ss[threadIdx.x >> 6] = s; qq[threadIdx.x >> 6] = q; }
    __syncthreads();
    if (threadIdx.x == 0) {
        sbuf[row] = ss[0] + ss[1] + ss[2] + ss[3];
        qbuf[row] = qq[0] + qq[1] + qq[2] + qq[3];
    }
}

__global__ void k_tr(const float* __restrict__ sbuf, const float* __restrict__ qbuf,
                     float* __restrict__ trbuf, float* __restrict__ strbuf) {
    const int b = blockIdx.x, t = threadIdx.x;
    const float invn = 1.f / (float)HW, invn2 = invn * invn;
    float sv = sbuf[b * C + t];
    float v = qbuf[b * C + t] * invn - sv * sv * invn2;
    v = wave_sum(v);
    __shared__ float red[4];
    if ((t & 63) == 0) red[t >> 6] = v;
    __syncthreads();
    if (t == 0) {
        float tr = red[0] + red[1] + red[2] + red[3];
        trbuf[b] = tr;
        strbuf[b] = sqrtf(tr);
    }
}

// ---------------------------------------------------------------------------
// gram split-K, XCD-swizzled flat grid (2240 blocks), double-buffered LDS,
// 16 KB buffers (K=32 chunks) -> 32 KB LDS -> ~5 blocks/CU.
// ---------------------------------------------------------------------------
__global__ __launch_bounds__(256) void k_gram_split(
    const unsigned short* __restrict__ Xh, const unsigned short* __restrict__ Xl,
    float* __restrict__ part) {
    const int bid = blockIdx.x;
    const int x8 = bid & 7;
    const int t8 = bid >> 3;
    const int pairIdx = t8 % 10;
    const int ghi = t8 / 10;
    const int g = ghi * 8 + x8;       // 0..223
    const int b = g & 31;
    const int z = g >> 5;             // 0..6

    int p = pairIdx, tm = 0, rem = 4;
    while (p >= rem) { p -= rem; ++tm; --rem; }
    const int tn = tm + p;

    const int tid = threadIdx.x, wave = tid >> 6, lane = tid & 63;
    const int wr = wave >> 1, wc = wave & 1;

    __shared__ __align__(16) unsigned short lds[2][4][2048]; // [buf][op][kq(4)][row(64)][8]

    const size_t matAB = (size_t)b * C * (size_t)HW;
    const unsigned short* src;
    {
        const unsigned short* s0 = (wave == 0) ? Xh : (wave == 1) ? Xl : (wave == 2) ? Xh : Xl;
        const int r0 = (wave < 2) ? tm * 64 : tn * 64;
        src = s0 + matAB + (size_t)(r0 + lane) * HW + z * KCHUNK;
    }

    f4v acc[2][2] = {};
    const int q = lane >> 4, r = lane & 15;
    const int mA0 = q * 512 + (wr * 32 + r) * 8;
    const int nB0 = q * 512 + (wc * 32 + r) * 8;

    // prologue stage into buf 0
#pragma unroll
    for (int c = 0; c < 4; ++c) stage16(src + c * 8, &lds[0][wave][c * 512]);

    for (int s = 0; s < KCHUNK / 32; ++s) {
        const int cb = s & 1, nb = cb ^ 1;
        __syncthreads();
        if (s < KCHUNK / 32 - 1) {
            const int k0 = (s + 1) * 32;
#pragma unroll
            for (int c = 0; c < 4; ++c) stage16(src + k0 + c * 8, &lds[nb][wave][c * 512]);
        }
        b8v ah0 = *(const b8v*)&lds[cb][0][mA0];
        b8v ah1 = *(const b8v*)&lds[cb][0][mA0 + 128];
        b8v al0 = *(const b8v*)&lds[cb][1][mA0];
        b8v al1 = *(const b8v*)&lds[cb][1][mA0 + 128];
        b8v bh0 = *(const b8v*)&lds[cb][2][nB0];
        b8v bh1 = *(const b8v*)&lds[cb][2][nB0 + 128];
        b8v bl0 = *(const b8v*)&lds[cb][3][nB0];
        b8v bl1 = *(const b8v*)&lds[cb][3][nB0 + 128];

        acc[0][0] = __builtin_amdgcn_mfma_f32_16x16x32_bf16(ah0, bh0, acc[0][0], 0, 0, 0);
        acc[0][0] = __builtin_amdgcn_mfma_f32_16x16x32_bf16(ah0, bl0, acc[0][0], 0, 0, 0);
        acc[0][0] = __builtin_amdgcn_mfma_f32_16x16x32_bf16(al0, bh0, acc[0][0], 0, 0, 0);
        acc[0][1] = __builtin_amdgcn_mfma_f32_16x16x32_bf16(ah0, bh1, acc[0][1], 0, 0, 0);
        acc[0][1] = __builtin_amdgcn_mfma_f32_16x16x32_bf16(ah0, bl1, acc[0][1], 0, 0, 0);
        acc[0][1] = __builtin_amdgcn_mfma_f32_16x16x32_bf16(al0, bh1, acc[0][1], 0, 0, 0);
        acc[1][0] = __builtin_amdgcn_mfma_f32_16x16x32_bf16(ah1, bh0, acc[1][0], 0, 0, 0);
        acc[1][0] = __builtin_amdgcn_mfma_f32_16x16x32_bf16(ah1, bl0, acc[1][0], 0, 0, 0);
        acc[1][0] = __builtin_amdgcn_mfma_f32_16x16x32_bf16(al1, bh0, acc[1][0], 0, 0, 0);
        acc[1][1] = __builtin_amdgcn_mfma_f32_16x16x32_bf16(ah1, bh1, acc[1][1], 0, 0, 0);
        acc[1][1] = __builtin_amdgcn_mfma_f32_16x16x32_bf16(ah1, bl1, acc[1][1], 0, 0, 0);
        acc[1][1] = __builtin_amdgcn_mfma_f32_16x16x32_bf16(al1, bh1, acc[1][1], 0, 0, 0);
    }

    float* pt = part + (((size_t)pairIdx * BATCH + b) * KSPLIT + z) * 4096;
#pragma unroll
    for (int rt = 0; rt < 2; ++rt)
#pragma unroll
        for (int ct = 0; ct < 2; ++ct)
#pragma unroll
            for (int reg = 0; reg < 4; ++reg) {
                int row = wr * 32 + rt * 16 + q * 4 + reg;
                int col = wc * 32 + ct * 16 + r;
                pt[row * 64 + col] = acc[rt][ct][reg];
            }
}

// ---------------------------------------------------------------------------
// reduce partials -> a and z0, mirrored via LDS transpose
// ---------------------------------------------------------------------------
__global__ __launch_bounds__(256) void k_reduce(
    const float* __restrict__ part, const float* __restrict__ sbuf,
    const float* __restrict__ trbuf,
    unsigned short* __restrict__ Ahh, unsigned short* __restrict__ All,
    unsigned short* __restrict__ Zhh, unsigned short* __restrict__ Zll) {
    const int b = blockIdx.y;
    int p = blockIdx.x, tm = 0, rem = 4;
    while (p >= rem) { p -= rem; ++tm; --rem; }
    const int tn = tm + p;

    const float* pb = part + ((size_t)blockIdx.x * BATCH + b) * KSPLIT * 4096;
    const int t = threadIdx.x;
    const int row = t >> 2, c0 = (t & 3) * 16;

    float s[16];
#pragma unroll
    for (int u = 0; u < 16; ++u) s[u] = 0.f;
    for (int sp = 0; sp < KSPLIT; ++sp) {
        const float* q4 = pb + sp * 4096 + row * 64 + c0;
#pragma unroll
        for (int u4 = 0; u4 < 4; ++u4) {
            float4 v = *(const float4*)(q4 + u4 * 4);
            s[u4 * 4 + 0] += v.x; s[u4 * 4 + 1] += v.y;
            s[u4 * 4 + 2] += v.z; s[u4 * 4 + 3] += v.w;
        }
    }

    const float invn = 1.f / (float)HW, invn2 = invn * invn;
    const float tr = trbuf[b];
    const int gi = tm * 64 + row;
    const float si = sbuf[b * C + gi];
    const size_t mo = (size_t)b * C * C;

    __shared__ unsigned short tAh[64][66], tAl[64][66], tZh[64][66], tZl[64][66];
    unsigned short vAh[16], vAl[16], vZh[16], vZl[16];
#pragma unroll
    for (int u = 0; u < 16; ++u) {
        int gj = tn * 64 + c0 + u;
        float sj = sbuf[b * C + gj];
        float a = (s[u] * invn - si * sj * invn2) / tr;
        split2(a, vAh[u], vAl[u]);
        float zv = ((gi == gj) ? 1.5f : 0.f) - 0.5f * a;
        split2(zv, vZh[u], vZl[u]);
        tAh[row][c0 + u] = vAh[u]; tAl[row][c0 + u] = vAl[u];
        tZh[row][c0 + u] = vZh[u]; tZl[row][c0 + u] = vZl[u];
    }
    size_t off = mo + (size_t)gi * C + tn * 64 + c0;
#pragma unroll
    for (int u4 = 0; u4 < 4; ++u4) {
        *(ushort4*)&Ahh[off + u4 * 4] = *(ushort4*)&vAh[u4 * 4];
        *(ushort4*)&All[off + u4 * 4] = *(ushort4*)&vAl[u4 * 4];
        *(ushort4*)&Zhh[off + u4 * 4] = *(ushort4*)&vZh[u4 * 4];
        *(ushort4*)&Zll[off + u4 * 4] = *(ushort4*)&vZl[u4 * 4];
    }
    if (tm != tn) {
        __syncthreads();
        const int mr = t >> 2, mc0 = (t & 3) * 16;
        size_t moff = mo + (size_t)(tn * 64 + mr) * C + tm * 64 + mc0;
        unsigned short wAh[16], wAl[16], wZh[16], wZl[16];
#pragma unroll
        for (int u = 0; u < 16; ++u) {
            wAh[u] = tAh[mc0 + u][mr]; wAl[u] = tAl[mc0 + u][mr];
            wZh[u] = tZh[mc0 + u][mr]; wZl[u] = tZl[mc0 + u][mr];
        }
#pragma unroll
        for (int u4 = 0; u4 < 4; ++u4) {
            *(ushort4*)&Ahh[moff + u4 * 4] = *(ushort4*)&wAh[u4 * 4];
            *(ushort4*)&All[moff + u4 * 4] = *(ushort4*)&wAl[u4 * 4];
            *(ushort4*)&Zhh[moff + u4 * 4] = *(ushort4*)&wZh[u4 * 4];
            *(ushort4*)&Zll[moff + u4 * 4] = *(ushort4*)&wZl[u4 * 4];
        }
    }
}

// ---------------------------------------------------------------------------
// NS core: one wave owns a full 64x64 tile; K=256; fragments loaded directly
// global->VGPR (row-major, 16B contiguous per lane), register double-buffered.
// No LDS, no barriers, no vmcnt(0) drains.
// ---------------------------------------------------------------------------
__device__ __forceinline__ void wave_gemm64(
    const unsigned short* __restrict__ Ah, const unsigned short* __restrict__ Al,
    const unsigned short* __restrict__ Bh, const unsigned short* __restrict__ Bl,
    int rowA, int rowB, f4v acc[4][4]) {
    const int lane = threadIdx.x & 63;
    const int q = lane >> 4, r = lane & 15;
    size_t oA[4], oB[4];
#pragma unroll
    for (int i = 0; i < 4; ++i) {
        oA[i] = (size_t)(rowA + i * 16 + r) * C + q * 8;
        oB[i] = (size_t)(rowB + i * 16 + r) * C + q * 8;
    }
    b8v fAh[2][4], fAl[2][4], fBh[2][4], fBl[2][4];
#define LD(buf, k0)                                           \
    do {                                                      \
        for (int i = 0; i < 4; ++i) {                         \
            fAh[buf][i] = *(const b8v*)(Ah + oA[i] + (k0));   \
            fAl[buf][i] = *(const b8v*)(Al + oA[i] + (k0));   \
            fBh[buf][i] = *(const b8v*)(Bh + oB[i] + (k0));   \
            fBl[buf][i] = *(const b8v*)(Bl + oB[i] + (k0));   \
        }                                                     \
    } while (0)

    LD(0, 0);
#pragma unroll
    for (int kc = 0; kc < 8; ++kc) {
        const int cb = kc & 1, nb = cb ^ 1;
        if (kc < 7) LD(nb, (kc + 1) * 32);
#pragma unroll
        for (int i = 0; i < 4; ++i)
#pragma unroll
            for (int j = 0; j < 4; ++j) {
                acc[i][j] = __builtin_amdgcn_mfma_f32_16x16x32_bf16(fAh[cb][i], fBh[cb][j], acc[i][j], 0, 0, 0);
                acc[i][j] = __builtin_amdgcn_mfma_f32_16x16x32_bf16(fAh[cb][i], fBl[cb][j], acc[i][j], 0, 0, 0);
                acc[i][j] = __builtin_amdgcn_mfma_f32_16x16x32_bf16(fAl[cb][i], fBh[cb][j], acc[i][j], 0, 0, 0);
            }
    }
#undef LD
}

// MODE 0: D = acc ; MODE 1: D = 1.5I - 0.5 acc ; MODE 2: triuvec(acc*sqrt(tr))
template <int MODE>
__global__ __launch_bounds__(64) void k_t64(
    const unsigned short* __restrict__ Ah, const unsigned short* __restrict__ Al,
    const unsigned short* __restrict__ Bh, const unsigned short* __restrict__ Bl,
    unsigned short* __restrict__ Dh, unsigned short* __restrict__ Dl,
    float* __restrict__ outF, const float* __restrict__ strbuf) {
    const int b = blockIdx.y;
    int tm, tn;
    if (MODE == 2) {
        int p = blockIdx.x, rem = 4; tm = 0;
        while (p >= rem) { p -= rem; ++tm; --rem; }
        tn = tm + p;
    } else {
        tm = blockIdx.x >> 2;
        tn = blockIdx.x & 3;
    }
    const size_t mo = (size_t)b * C * C;
    f4v acc[4][4] = {};
    wave_gemm64(Ah + mo, Al + mo, Bh + mo, Bl + mo, tm * 64, tn * 64, acc);

    const int lane = threadIdx.x & 63, q = lane >> 4, r = lane & 15;
    if (MODE == 2) {
        const float sc = strbuf[b];
#pragma unroll
        for (int i = 0; i < 4; ++i)
#pragma unroll
            for (int j = 0; j < 4; ++j) {
                const int gj = tn * 64 + j * 16 + r;
#pragma unroll
                for (int reg = 0; reg < 4; ++reg) {
                    const int gi = tm * 64 + i * 16 + q * 4 + reg;
                    if (gj >= gi)
                        outF[(size_t)b * OUTROW + (size_t)(gi * C - (gi * (gi - 1)) / 2) +
                             (gj - gi)] = acc[i][j][reg] * sc;
                }
            }
    } else {
#pragma unroll
        for (int i = 0; i < 4; ++i)
#pragma unroll
            for (int j = 0; j < 4; ++j) {
                const int gj = tn * 64 + j * 16 + r;
#pragma unroll
                for (int reg = 0; reg < 4; ++reg) {
                    const int gi = tm * 64 + i * 16 + q * 4 + reg;
                    float v = acc[i][j][reg];
                    if (MODE == 1) v = ((gi == gj) ? 1.5f : 0.f) - 0.5f * v;
                    unsigned short h, l;
                    split2(v, h, l);
                    Dh[mo + (size_t)gi * C + gj] = h;
                    Dl[mo + (size_t)gi * C + gj] = l;
                }
            }
    }
}

// fused Ynew = Y@T (z=0), Znew = T@Z (z=1)
__global__ __launch_bounds__(64) void k_yz64(
    const unsigned short* __restrict__ Yh, const unsigned short* __restrict__ Yl,
    const unsigned short* __restrict__ Th, const unsigned short* __restrict__ Tl,
    const unsigned short* __restrict__ Zh, const unsigned short* __restrict__ Zl,
    unsigned short* __restrict__ Ynh, unsigned short* __restrict__ Ynl,
    unsigned short* __restrict__ Znh, unsigned short* __restrict__ Znl) {
    const int b = blockIdx.y, zz = blockIdx.z;
    const int tm = blockIdx.x >> 2, tn = blockIdx.x & 3;
    const unsigned short* Ah = zz ? Th : Yh;
    const unsigned short* Al = zz ? Tl : Yl;
    const unsigned short* Bh = zz ? Zh : Th;
    const unsigned short* Bl = zz ? Zl : Tl;
    unsigned short* Dh = zz ? Znh : Ynh;
    unsigned short* Dl = zz ? Znl : Ynl;

    const size_t mo = (size_t)b * C * C;
    f4v acc[4][4] = {};
    wave_gemm64(Ah + mo, Al + mo, Bh + mo, Bl + mo, tm * 64, tn * 64, acc);

    const int lane = threadIdx.x & 63, q = lane >> 4, r = lane & 15;
#pragma unroll
    for (int i = 0; i < 4; ++i)
#pragma unroll
        for (int j = 0; j < 4; ++j) {
            const int gj = tn * 64 + j * 16 + r;
#pragma unroll
            for (int reg = 0; reg < 4; ++reg) {
                const int gi = tm * 64 + i * 16 + q * 4 + reg;
                unsigned short h, l;
                split2(acc[i][j][reg], h, l);
                Dh[mo + (size_t)gi * C + gj] = h;
                Dl[mo + (size_t)gi * C + gj] = l;
            }
        }
}

// ---------------------------------------------------------------------------
extern "C" void kernel_launch(void* const* d_in, const int* in_sizes, int n_in,
                              void* d_out, int out_size, void* d_ws, size_t ws_size,
                              hipStream_t stream) {
    const float* x = (const float*)d_in[0];
    float* out = (float*)d_out;

    unsigned short* W = (unsigned short*)d_ws;
    const size_t XN = (size_t)BATCH * C * HW;
    const size_t M = (size_t)BATCH * C * C;
    unsigned short* XH = W;
    unsigned short* XL = XH + XN;
    float* sbuf = (float*)(XL + XN);
    float* qbuf = sbuf + BATCH * C;
    float* trbuf = qbuf + BATCH * C;
    float* strbuf = trbuf + BATCH;
    unsigned short* P = (unsigned short*)(strbuf + BATCH);
    unsigned short* PA_h = P + 0 * M; unsigned short* PA_l = P + 1 * M;
    unsigned short* PB_h = P + 2 * M; unsigned short* PB_l = P + 3 * M;
    unsigned short* PC_h = P + 4 * M; unsigned short* PC_l = P + 5 * M;
    unsigned short* PD_h = P + 6 * M; unsigned short* PD_l = P + 7 * M;
    unsigned short* PE_h = P + 8 * M; unsigned short* PE_l = P + 9 * M;
    // fp32 partials alias PC..PE + beyond (dead until Y0 is written)
    float* part = (float*)PC_h;   // 10*32*7*4096 floats

    k_prep<<<dim3(BATCH * C), 256, 0, stream>>>(x, XH, XL, sbuf, qbuf);
    k_tr<<<dim3(BATCH), 256, 0, stream>>>(sbuf, qbuf, trbuf, strbuf);
    k_gram_split<<<dim3(10 * BATCH * KSPLIT), 256, 0, stream>>>(XH, XL, part);
    k_reduce<<<dim3(10, BATCH), 256, 0, stream>>>(part, sbuf, trbuf,
                                                  PA_h, PA_l, PB_h, PB_l);

    dim3 g16(16, BATCH);
    // Y0 = a @ z0 -> PC
    k_t64<0><<<g16, 64, 0, stream>>>(PA_h, PA_l, PB_h, PB_l, PC_h, PC_l, nullptr, strbuf);
    // it0: T0 = 1.5I - 0.5 Z0@Y0 = PB@PC -> PD ; Y1 = PC@PD -> PA ; Z1 = PD@PB -> PE
    k_t64<1><<<g16, 64, 0, stream>>>(PB_h, PB_l, PC_h, PC_l, PD_h, PD_l, nullptr, strbuf);
    k_yz64<<<dim3(16, BATCH, 2), 64, 0, stream>>>(PC_h, PC_l, PD_h, PD_l, PB_h, PB_l,
                                                  PA_h, PA_l, PE_h, PE_l);
    // it1: T1 = PE@PA -> PB ; Y2 = PA@PB -> PC ; Z2 = PB@PE -> PD
    k_t64<1><<<g16, 64, 0, stream>>>(PE_h, PE_l, PA_h, PA_l, PB_h, PB_l, nullptr, strbuf);
    k_yz64<<<dim3(16, BATCH, 2), 64, 0, stream>>>(PA_h, PA_l, PB_h, PB_l, PE_h, PE_l,
                                                  PC_h, PC_l, PD_h, PD_l);
    // it2: T2 = PD@PC -> PA ; Y3 = PC@PA -> PB ; Z3 = PA@PD -> PE
    k_t64<1><<<g16, 64, 0, stream>>>(PD_h, PD_l, PC_h, PC_l, PA_h, PA_l, nullptr, strbuf);
    k_yz64<<<dim3(16, BATCH, 2), 64, 0, stream>>>(PC_h, PC_l, PA_h, PA_l, PD_h, PD_l,
                                                  PB_h, PB_l, PE_h, PE_l);
    // it3: T3 = PE@PB -> PC ; out = triuvec((PB@PC) * sqrt(tr))
    k_t64<1><<<g16, 64, 0, stream>>>(PE_h, PE_l, PB_h, PB_l, PC_h, PC_l, nullptr, strbuf);
    k_t64<2><<<dim3(10, BATCH), 64, 0, stream>>>(PB_h, PB_l, PC_h, PC_l, nullptr, nullptr,
                                                 out, strbuf);
}

// Round 7
// 405.747 us; speedup vs baseline: 1.0850x; 1.0850x over previous
//
#include <hip/hip_runtime.h>
#include <hip/hip_bf16.h>
#include <math.h>

#define BATCH 32
#define C 256
#define HW 3136
#define OUTROW 32896
#define KSPLIT 7
#define KCHUNK 448   // HW / KSPLIT, multiple of 32

typedef __bf16 b8v __attribute__((ext_vector_type(8)));
typedef float  f4v __attribute__((ext_vector_type(4)));

__device__ __forceinline__ unsigned short f2bf(float f) {
    union { float f; unsigned u; } v; v.f = f;
    unsigned r = v.u + 0x7FFFu + ((v.u >> 16) & 1u);
    return (unsigned short)(r >> 16);
}
__device__ __forceinline__ float bf2f(unsigned short h) {
    union { unsigned u; float f; } v; v.u = ((unsigned)h) << 16; return v.f;
}
__device__ __forceinline__ void split2(float x, unsigned short& h, unsigned short& l) {
    h = f2bf(x);
    l = f2bf(x - bf2f(h));
}

__device__ __forceinline__ float wave_sum(float v) {
    for (int o = 32; o; o >>= 1) v += __shfl_down(v, o, 64);
    return v;
}

// ---------------------------------------------------------------------------
// prep: x -> hi/lo bf16 split, per-row sum and sum-of-squares
// ---------------------------------------------------------------------------
__global__ void k_prep(const float* __restrict__ x, unsigned short* __restrict__ xh,
                       unsigned short* __restrict__ xl, float* __restrict__ sbuf,
                       float* __restrict__ qbuf) {
    const int row = blockIdx.x;
    const float4* xr = (const float4*)(x + (size_t)row * HW);
    ushort4* hr = (ushort4*)(xh + (size_t)row * HW);
    ushort4* lr = (ushort4*)(xl + (size_t)row * HW);
    float s = 0.f, q = 0.f;
    for (int c = threadIdx.x; c < HW / 4; c += 256) {
        float4 v = xr[c];
        ushort4 h, l;
        split2(v.x, h.x, l.x); split2(v.y, h.y, l.y);
        split2(v.z, h.z, l.z); split2(v.w, h.w, l.w);
        hr[c] = h; lr[c] = l;
        s += v.x + v.y + v.z + v.w;
        q += v.x * v.x + v.y * v.y + v.z * v.z + v.w * v.w;
    }
    s = wave_sum(s); q = wave_sum(q);
    __shared__ float ss[4], qq[4];
    if ((threadIdx.x & 63) == 0) { ss[threadIdx.x >> 6] = s; qq[threadIdx.x >> 6] = q; }
    __syncthreads();
    if (threadIdx.x == 0) {
        sbuf[row] = ss[0] + ss[1] + ss[2] + ss[3];
        qbuf[row] = qq[0] + qq[1] + qq[2] + qq[3];
    }
}

__global__ void k_tr(const float* __restrict__ sbuf, const float* __restrict__ qbuf,
                     float* __restrict__ trbuf, float* __restrict__ strbuf) {
    const int b = blockIdx.x, t = threadIdx.x;
    const float invn = 1.f / (float)HW, invn2 = invn * invn;
    float sv = sbuf[b * C + t];
    float v = qbuf[b * C + t] * invn - sv * sv * invn2;
    v = wave_sum(v);
    __shared__ float red[4];
    if ((t & 63) == 0) red[t >> 6] = v;
    __syncthreads();
    if (t == 0) {
        float tr = red[0] + red[1] + red[2] + red[3];
        trbuf[b] = tr;
        strbuf[b] = sqrtf(tr);
    }
}

// ---------------------------------------------------------------------------
// gram split-K: 1-wave blocks, 64x64 wave tile, direct global->VGPR fragment
// loads (no LDS, no barriers), register double-buffered, XCD-pinned (b,z).
// Grid: 2240 x 64 threads.
// ---------------------------------------------------------------------------
__global__ __launch_bounds__(64) void k_gram_split(
    const unsigned short* __restrict__ Xh, const unsigned short* __restrict__ Xl,
    float* __restrict__ part) {
    const int bid = blockIdx.x;
    const int x8 = bid & 7;
    const int t8 = bid >> 3;
    const int pairIdx = t8 % 10;
    const int g = (t8 / 10) * 8 + x8;   // 0..223, pinned to XCD x8
    const int b = g & 31;
    const int z = g >> 5;               // 0..6

    int p = pairIdx, tm = 0, rem = 4;
    while (p >= rem) { p -= rem; ++tm; --rem; }
    const int tn = tm + p;

    const int lane = threadIdx.x & 63;
    const int q = lane >> 4, r = lane & 15;
    const size_t mat = (size_t)b * C * (size_t)HW;
    const int kbase = z * KCHUNK + q * 8;

    size_t oA[4], oB[4];
#pragma unroll
    for (int i = 0; i < 4; ++i) {
        oA[i] = mat + (size_t)(tm * 64 + i * 16 + r) * HW + kbase;
        oB[i] = mat + (size_t)(tn * 64 + i * 16 + r) * HW + kbase;
    }

    f4v acc[4][4] = {};
    b8v fAh[2][4], fAl[2][4], fBh[2][4], fBl[2][4];
#define LDG(buf, k0)                                          \
    do {                                                      \
        for (int i = 0; i < 4; ++i) {                         \
            fAh[buf][i] = *(const b8v*)(Xh + oA[i] + (k0));   \
            fAl[buf][i] = *(const b8v*)(Xl + oA[i] + (k0));   \
            fBh[buf][i] = *(const b8v*)(Xh + oB[i] + (k0));   \
            fBl[buf][i] = *(const b8v*)(Xl + oB[i] + (k0));   \
        }                                                     \
    } while (0)

    LDG(0, 0);
#pragma unroll
    for (int kc = 0; kc < KCHUNK / 32; ++kc) {
        const int cb = kc & 1, nb = cb ^ 1;
        if (kc < KCHUNK / 32 - 1) LDG(nb, (kc + 1) * 32);
#pragma unroll
        for (int i = 0; i < 4; ++i)
#pragma unroll
            for (int j = 0; j < 4; ++j) {
                acc[i][j] = __builtin_amdgcn_mfma_f32_16x16x32_bf16(fAh[cb][i], fBh[cb][j], acc[i][j], 0, 0, 0);
                acc[i][j] = __builtin_amdgcn_mfma_f32_16x16x32_bf16(fAh[cb][i], fBl[cb][j], acc[i][j], 0, 0, 0);
                acc[i][j] = __builtin_amdgcn_mfma_f32_16x16x32_bf16(fAl[cb][i], fBh[cb][j], acc[i][j], 0, 0, 0);
            }
    }
#undef LDG

    float* pt = part + (((size_t)pairIdx * BATCH + b) * KSPLIT + z) * 4096;
#pragma unroll
    for (int i = 0; i < 4; ++i)
#pragma unroll
        for (int j = 0; j < 4; ++j)
#pragma unroll
            for (int reg = 0; reg < 4; ++reg) {
                int row = i * 16 + q * 4 + reg;
                int col = j * 16 + r;
                pt[row * 64 + col] = acc[i][j][reg];
            }
}

// ---------------------------------------------------------------------------
// reduce partials -> a and z0, mirrored via LDS transpose
// ---------------------------------------------------------------------------
__global__ __launch_bounds__(256) void k_reduce(
    const float* __restrict__ part, const float* __restrict__ sbuf,
    const float* __restrict__ trbuf,
    unsigned short* __restrict__ Ahh, unsigned short* __restrict__ All,
    unsigned short* __restrict__ Zhh, unsigned short* __restrict__ Zll) {
    const int b = blockIdx.y;
    int p = blockIdx.x, tm = 0, rem = 4;
    while (p >= rem) { p -= rem; ++tm; --rem; }
    const int tn = tm + p;

    const float* pb = part + ((size_t)blockIdx.x * BATCH + b) * KSPLIT * 4096;
    const int t = threadIdx.x;
    const int row = t >> 2, c0 = (t & 3) * 16;

    float s[16];
#pragma unroll
    for (int u = 0; u < 16; ++u) s[u] = 0.f;
    for (int sp = 0; sp < KSPLIT; ++sp) {
        const float* q4 = pb + sp * 4096 + row * 64 + c0;
#pragma unroll
        for (int u4 = 0; u4 < 4; ++u4) {
            float4 v = *(const float4*)(q4 + u4 * 4);
            s[u4 * 4 + 0] += v.x; s[u4 * 4 + 1] += v.y;
            s[u4 * 4 + 2] += v.z; s[u4 * 4 + 3] += v.w;
        }
    }

    const float invn = 1.f / (float)HW, invn2 = invn * invn;
    const float tr = trbuf[b];
    const int gi = tm * 64 + row;
    const float si = sbuf[b * C + gi];
    const size_t mo = (size_t)b * C * C;

    __shared__ unsigned short tAh[64][66], tAl[64][66], tZh[64][66], tZl[64][66];
    unsigned short vAh[16], vAl[16], vZh[16], vZl[16];
#pragma unroll
    for (int u = 0; u < 16; ++u) {
        int gj = tn * 64 + c0 + u;
        float sj = sbuf[b * C + gj];
        float a = (s[u] * invn - si * sj * invn2) / tr;
        split2(a, vAh[u], vAl[u]);
        float zv = ((gi == gj) ? 1.5f : 0.f) - 0.5f * a;
        split2(zv, vZh[u], vZl[u]);
        tAh[row][c0 + u] = vAh[u]; tAl[row][c0 + u] = vAl[u];
        tZh[row][c0 + u] = vZh[u]; tZl[row][c0 + u] = vZl[u];
    }
    size_t off = mo + (size_t)gi * C + tn * 64 + c0;
#pragma unroll
    for (int u4 = 0; u4 < 4; ++u4) {
        *(ushort4*)&Ahh[off + u4 * 4] = *(ushort4*)&vAh[u4 * 4];
        *(ushort4*)&All[off + u4 * 4] = *(ushort4*)&vAl[u4 * 4];
        *(ushort4*)&Zhh[off + u4 * 4] = *(ushort4*)&vZh[u4 * 4];
        *(ushort4*)&Zll[off + u4 * 4] = *(ushort4*)&vZl[u4 * 4];
    }
    if (tm != tn) {
        __syncthreads();
        const int mr = t >> 2, mc0 = (t & 3) * 16;
        size_t moff = mo + (size_t)(tn * 64 + mr) * C + tm * 64 + mc0;
        unsigned short wAh[16], wAl[16], wZh[16], wZl[16];
#pragma unroll
        for (int u = 0; u < 16; ++u) {
            wAh[u] = tAh[mc0 + u][mr]; wAl[u] = tAl[mc0 + u][mr];
            wZh[u] = tZh[mc0 + u][mr]; wZl[u] = tZl[mc0 + u][mr];
        }
#pragma unroll
        for (int u4 = 0; u4 < 4; ++u4) {
            *(ushort4*)&Ahh[moff + u4 * 4] = *(ushort4*)&wAh[u4 * 4];
            *(ushort4*)&All[moff + u4 * 4] = *(ushort4*)&wAl[u4 * 4];
            *(ushort4*)&Zhh[moff + u4 * 4] = *(ushort4*)&wZh[u4 * 4];
            *(ushort4*)&Zll[moff + u4 * 4] = *(ushort4*)&wZl[u4 * 4];
        }
    }
}

// ---------------------------------------------------------------------------
// NS core: one wave owns a 64x64 tile; K=256; direct global->VGPR loads,
// register double-buffered. No LDS, no barriers.
// ---------------------------------------------------------------------------
__device__ __forceinline__ void wave_gemm64(
    const unsigned short* __restrict__ Ah, const unsigned short* __restrict__ Al,
    const unsigned short* __restrict__ Bh, const unsigned short* __restrict__ Bl,
    int rowA, int rowB, f4v acc[4][4]) {
    const int lane = threadIdx.x & 63;
    const int q = lane >> 4, r = lane & 15;
    size_t oA[4], oB[4];
#pragma unroll
    for (int i = 0; i < 4; ++i) {
        oA[i] = (size_t)(rowA + i * 16 + r) * C + q * 8;
        oB[i] = (size_t)(rowB + i * 16 + r) * C + q * 8;
    }
    b8v fAh[2][4], fAl[2][4], fBh[2][4], fBl[2][4];
#define LD(buf, k0)                                           \
    do {                                                      \
        for (int i = 0; i < 4; ++i) {                         \
            fAh[buf][i] = *(const b8v*)(Ah + oA[i] + (k0));   \
            fAl[buf][i] = *(const b8v*)(Al + oA[i] + (k0));   \
            fBh[buf][i] = *(const b8v*)(Bh + oB[i] + (k0));   \
            fBl[buf][i] = *(const b8v*)(Bl + oB[i] + (k0));   \
        }                                                     \
    } while (0)

    LD(0, 0);
#pragma unroll
    for (int kc = 0; kc < 8; ++kc) {
        const int cb = kc & 1, nb = cb ^ 1;
        if (kc < 7) LD(nb, (kc + 1) * 32);
#pragma unroll
        for (int i = 0; i < 4; ++i)
#pragma unroll
            for (int j = 0; j < 4; ++j) {
                acc[i][j] = __builtin_amdgcn_mfma_f32_16x16x32_bf16(fAh[cb][i], fBh[cb][j], acc[i][j], 0, 0, 0);
                acc[i][j] = __builtin_amdgcn_mfma_f32_16x16x32_bf16(fAh[cb][i], fBl[cb][j], acc[i][j], 0, 0, 0);
                acc[i][j] = __builtin_amdgcn_mfma_f32_16x16x32_bf16(fAl[cb][i], fBh[cb][j], acc[i][j], 0, 0, 0);
            }
    }
#undef LD
}

// MODE 0: D = acc ; MODE 1: D = 1.5I - 0.5 acc ; MODE 2: triuvec(acc*sqrt(tr))
// XCD-pinned flat grid: batch b always lands on XCD b%8.
template <int MODE>
__global__ __launch_bounds__(64) void k_t64(
    const unsigned short* __restrict__ Ah, const unsigned short* __restrict__ Al,
    const unsigned short* __restrict__ Bh, const unsigned short* __restrict__ Bl,
    unsigned short* __restrict__ Dh, unsigned short* __restrict__ Dl,
    float* __restrict__ outF, const float* __restrict__ strbuf) {
    const int bid = blockIdx.x;
    const int x8 = bid & 7;
    const int w = bid >> 3;
    int b, tm, tn;
    if (MODE == 2) {
        b = x8 + 8 * (w / 10);            // 320 blocks: 4 batches/XCD x 10 tiles
        int p = w % 10, rem = 4; tm = 0;
        while (p >= rem) { p -= rem; ++tm; --rem; }
        tn = tm + p;
    } else {
        b = x8 + 8 * (w >> 4);            // 512 blocks: 4 batches/XCD x 16 tiles
        const int tile = w & 15;
        tm = tile >> 2; tn = tile & 3;
    }
    const size_t mo = (size_t)b * C * C;
    f4v acc[4][4] = {};
    wave_gemm64(Ah + mo, Al + mo, Bh + mo, Bl + mo, tm * 64, tn * 64, acc);

    const int lane = threadIdx.x & 63, q = lane >> 4, r = lane & 15;
    if (MODE == 2) {
        const float sc = strbuf[b];
#pragma unroll
        for (int i = 0; i < 4; ++i)
#pragma unroll
            for (int j = 0; j < 4; ++j) {
                const int gj = tn * 64 + j * 16 + r;
#pragma unroll
                for (int reg = 0; reg < 4; ++reg) {
                    const int gi = tm * 64 + i * 16 + q * 4 + reg;
                    if (gj >= gi)
                        outF[(size_t)b * OUTROW + (size_t)(gi * C - (gi * (gi - 1)) / 2) +
                             (gj - gi)] = acc[i][j][reg] * sc;
                }
            }
    } else {
#pragma unroll
        for (int i = 0; i < 4; ++i)
#pragma unroll
            for (int j = 0; j < 4; ++j) {
                const int gj = tn * 64 + j * 16 + r;
#pragma unroll
                for (int reg = 0; reg < 4; ++reg) {
                    const int gi = tm * 64 + i * 16 + q * 4 + reg;
                    float v = acc[i][j][reg];
                    if (MODE == 1) v = ((gi == gj) ? 1.5f : 0.f) - 0.5f * v;
                    unsigned short h, l;
                    split2(v, h, l);
                    Dh[mo + (size_t)gi * C + gj] = h;
                    Dl[mo + (size_t)gi * C + gj] = l;
                }
            }
    }
}

// fused Ynew = Y@T, Znew = T@Z ; XCD-pinned flat grid (1024 blocks)
__global__ __launch_bounds__(64) void k_yz64(
    const unsigned short* __restrict__ Yh, const unsigned short* __restrict__ Yl,
    const unsigned short* __restrict__ Th, const unsigned short* __restrict__ Tl,
    const unsigned short* __restrict__ Zh, const unsigned short* __restrict__ Zl,
    unsigned short* __restrict__ Ynh, unsigned short* __restrict__ Ynl,
    unsigned short* __restrict__ Znh, unsigned short* __restrict__ Znl) {
    const int bid = blockIdx.x;
    const int x8 = bid & 7;
    const int w = bid >> 3;                 // 0..127
    const int b = x8 + 8 * ((w >> 4) & 3);  // 4 batches per XCD
    const int zz = w >> 6;                  // 0: Y@T, 1: T@Z
    const int tile = w & 15;
    const int tm = tile >> 2, tn = tile & 3;

    const unsigned short* Ah = zz ? Th : Yh;
    const unsigned short* Al = zz ? Tl : Yl;
    const unsigned short* Bh = zz ? Zh : Th;
    const unsigned short* Bl = zz ? Zl : Tl;
    unsigned short* Dh = zz ? Znh : Ynh;
    unsigned short* Dl = zz ? Znl : Ynl;

    const size_t mo = (size_t)b * C * C;
    f4v acc[4][4] = {};
    wave_gemm64(Ah + mo, Al + mo, Bh + mo, Bl + mo, tm * 64, tn * 64, acc);

    const int lane = threadIdx.x & 63, q = lane >> 4, r = lane & 15;
#pragma unroll
    for (int i = 0; i < 4; ++i)
#pragma unroll
        for (int j = 0; j < 4; ++j) {
            const int gj = tn * 64 + j * 16 + r;
#pragma unroll
            for (int reg = 0; reg < 4; ++reg) {
                const int gi = tm * 64 + i * 16 + q * 4 + reg;
                unsigned short h, l;
                split2(acc[i][j][reg], h, l);
                Dh[mo + (size_t)gi * C + gj] = h;
                Dl[mo + (size_t)gi * C + gj] = l;
            }
        }
}

// ---------------------------------------------------------------------------
extern "C" void kernel_launch(void* const* d_in, const int* in_sizes, int n_in,
                              void* d_out, int out_size, void* d_ws, size_t ws_size,
                              hipStream_t stream) {
    const float* x = (const float*)d_in[0];
    float* out = (float*)d_out;

    unsigned short* W = (unsigned short*)d_ws;
    const size_t XN = (size_t)BATCH * C * HW;
    const size_t M = (size_t)BATCH * C * C;
    unsigned short* XH = W;
    unsigned short* XL = XH + XN;
    float* sbuf = (float*)(XL + XN);
    float* qbuf = sbuf + BATCH * C;
    float* trbuf = qbuf + BATCH * C;
    float* strbuf = trbuf + BATCH;
    unsigned short* P = (unsigned short*)(strbuf + BATCH);
    unsigned short* PA_h = P + 0 * M; unsigned short* PA_l = P + 1 * M;
    unsigned short* PB_h = P + 2 * M; unsigned short* PB_l = P + 3 * M;
    unsigned short* PC_h = P + 4 * M; unsigned short* PC_l = P + 5 * M;
    unsigned short* PD_h = P + 6 * M; unsigned short* PD_l = P + 7 * M;
    unsigned short* PE_h = P + 8 * M; unsigned short* PE_l = P + 9 * M;
    // fp32 partials alias PC..PE + beyond (dead until Y0 is written)
    float* part = (float*)PC_h;   // 10*32*7*4096 floats

    k_prep<<<dim3(BATCH * C), 256, 0, stream>>>(x, XH, XL, sbuf, qbuf);
    k_tr<<<dim3(BATCH), 256, 0, stream>>>(sbuf, qbuf, trbuf, strbuf);
    k_gram_split<<<dim3(10 * BATCH * KSPLIT), 64, 0, stream>>>(XH, XL, part);
    k_reduce<<<dim3(10, BATCH), 256, 0, stream>>>(part, sbuf, trbuf,
                                                  PA_h, PA_l, PB_h, PB_l);

    dim3 g512(512);
    // Y0 = a @ z0 -> PC
    k_t64<0><<<g512, 64, 0, stream>>>(PA_h, PA_l, PB_h, PB_l, PC_h, PC_l, nullptr, strbuf);
    // it0: T0 = 1.5I - 0.5 Z0@Y0 = PB@PC -> PD ; Y1 = PC@PD -> PA ; Z1 = PD@PB -> PE
    k_t64<1><<<g512, 64, 0, stream>>>(PB_h, PB_l, PC_h, PC_l, PD_h, PD_l, nullptr, strbuf);
    k_yz64<<<dim3(1024), 64, 0, stream>>>(PC_h, PC_l, PD_h, PD_l, PB_h, PB_l,
                                          PA_h, PA_l, PE_h, PE_l);
    // it1: T1 = PE@PA -> PB ; Y2 = PA@PB -> PC ; Z2 = PB@PE -> PD
    k_t64<1><<<g512, 64, 0, stream>>>(PE_h, PE_l, PA_h, PA_l, PB_h, PB_l, nullptr, strbuf);
    k_yz64<<<dim3(1024), 64, 0, stream>>>(PA_h, PA_l, PB_h, PB_l, PE_h, PE_l,
                                          PC_h, PC_l, PD_h, PD_l);
    // it2: T2 = PD@PC -> PA ; Y3 = PC@PA -> PB ; Z3 = PA@PD -> PE
    k_t64<1><<<g512, 64, 0, stream>>>(PD_h, PD_l, PC_h, PC_l, PA_h, PA_l, nullptr, strbuf);
    k_yz64<<<dim3(1024), 64, 0, stream>>>(PC_h, PC_l, PA_h, PA_l, PD_h, PD_l,
                                          PB_h, PB_l, PE_h, PE_l);
    // it3: T3 = PE@PB -> PC ; out = triuvec((PB@PC) * sqrt(tr))
    k_t64<1><<<g512, 64, 0, stream>>>(PE_h, PE_l, PB_h, PB_l, PC_h, PC_l, nullptr, strbuf);
    k_t64<2><<<dim3(320), 64, 0, stream>>>(PB_h, PB_l, PC_h, PC_l, nullptr, nullptr,
                                           out, strbuf);
}

// Round 8
// 372.836 us; speedup vs baseline: 1.1807x; 1.0883x over previous
//
#include <hip/hip_runtime.h>
#include <hip/hip_bf16.h>
#include <math.h>

#define BATCH 32
#define C 256
#define HW 3136
#define OUTROW 32896
#define KSPLIT 7
#define KCHUNK 448   // HW / KSPLIT
#define KC32 98      // HW / 32

// Fragment-major layouts (shorts):
//   X:  ((b*98 + kc)*256 + row)*32 + (k&31)
//   M:  ((b*8  + kc)*256 + row)*32 + (k&31)   (256x256 matrices)
// A wave's 16-lane fragment group (q=k/8 within kc, r=row low 4 bits) then
// reads 16 consecutive rows x 64 B = 1 KiB contiguous -> fully coalesced.

typedef __bf16 b8v __attribute__((ext_vector_type(8)));
typedef float  f4v __attribute__((ext_vector_type(4)));

__device__ __forceinline__ unsigned short f2bf(float f) {
    union { float f; unsigned u; } v; v.f = f;
    unsigned r = v.u + 0x7FFFu + ((v.u >> 16) & 1u);
    return (unsigned short)(r >> 16);
}
__device__ __forceinline__ float bf2f(unsigned short h) {
    union { unsigned u; float f; } v; v.u = ((unsigned)h) << 16; return v.f;
}
__device__ __forceinline__ void split2(float x, unsigned short& h, unsigned short& l) {
    h = f2bf(x);
    l = f2bf(x - bf2f(h));
}

__device__ __forceinline__ float wave_sum(float v) {
    for (int o = 32; o; o >>= 1) v += __shfl_down(v, o, 64);
    return v;
}

// ---------------------------------------------------------------------------
// prep: x -> hi/lo bf16 split in fragment-major X layout + row sums / sumsq
// ---------------------------------------------------------------------------
__global__ void k_prep(const float* __restrict__ x, unsigned short* __restrict__ xh,
                       unsigned short* __restrict__ xl, float* __restrict__ sbuf,
                       float* __restrict__ qbuf) {
    const int row = blockIdx.x;            // b*C + c
    const int b = row >> 8, c = row & 255;
    const float4* xr = (const float4*)(x + (size_t)row * HW);
    float s = 0.f, q = 0.f;
    for (int idx = threadIdx.x; idx < HW / 4; idx += 256) {
        const int k = idx * 4;
        const int kc = k >> 5, ko = k & 31;
        float4 v = xr[idx];
        ushort4 h, l;
        split2(v.x, h.x, l.x); split2(v.y, h.y, l.y);
        split2(v.z, h.z, l.z); split2(v.w, h.w, l.w);
        const size_t dst = ((size_t)(b * KC32 + kc) * 256 + c) * 32 + ko;
        *(ushort4*)&xh[dst] = h;
        *(ushort4*)&xl[dst] = l;
        s += v.x + v.y + v.z + v.w;
        q += v.x * v.x + v.y * v.y + v.z * v.z + v.w * v.w;
    }
    s = wave_sum(s); q = wave_sum(q);
    __shared__ float ss[4], qq[4];
    if ((threadIdx.x & 63) == 0) { ss[threadIdx.x >> 6] = s; qq[threadIdx.x >> 6] = q; }
    __syncthreads();
    if (threadIdx.x == 0) {
        sbuf[row] = ss[0] + ss[1] + ss[2] + ss[3];
        qbuf[row] = qq[0] + qq[1] + qq[2] + qq[3];
    }
}

__global__ void k_tr(const float* __restrict__ sbuf, const float* __restrict__ qbuf,
                     float* __restrict__ trbuf, float* __restrict__ strbuf) {
    const int b = blockIdx.x, t = threadIdx.x;
    const float invn = 1.f / (float)HW, invn2 = invn * invn;
    float sv = sbuf[b * C + t];
    float v = qbuf[b * C + t] * invn - sv * sv * invn2;
    v = wave_sum(v);
    __shared__ float red[4];
    if ((t & 63) == 0) red[t >> 6] = v;
    __syncthreads();
    if (t == 0) {
        float tr = red[0] + red[1] + red[2] + red[3];
        trbuf[b] = tr;
        strbuf[b] = sqrtf(tr);
    }
}

// ---------------------------------------------------------------------------
// gram split-K: 1-wave blocks, 64x64 tile, fragment-major coalesced loads,
// register dbuf, XCD-pinned. Grid 2240 x 64.
// ---------------------------------------------------------------------------
__global__ __launch_bounds__(64) void k_gram_split(
    const unsigned short* __restrict__ Xh, const unsigned short* __restrict__ Xl,
    float* __restrict__ part) {
    const int bid = blockIdx.x;
    const int x8 = bid & 7;
    const int t8 = bid >> 3;
    const int pairIdx = t8 % 10;
    const int g = (t8 / 10) * 8 + x8;   // 0..223, pinned to XCD x8
    const int b = g & 31;
    const int z = g >> 5;               // 0..6

    int p = pairIdx, tm = 0, rem = 4;
    while (p >= rem) { p -= rem; ++tm; --rem; }
    const int tn = tm + p;

    const int lane = threadIdx.x & 63;
    const int q = lane >> 4, r = lane & 15;
    const int kc0 = z * (KCHUNK / 32);            // first kc of this split
    const size_t matb = (size_t)b * KC32 * 8192;  // 256*32 = 8192 shorts per kc

    // fragment offsets within a kc slab (8192 shorts)
    int oA[4], oB[4];
#pragma unroll
    for (int i = 0; i < 4; ++i) {
        oA[i] = (tm * 64 + i * 16 + r) * 32 + q * 8;
        oB[i] = (tn * 64 + i * 16 + r) * 32 + q * 8;
    }

    f4v acc[4][4] = {};
    b8v fAh[2][4], fAl[2][4], fBh[2][4], fBl[2][4];
#define LDG(buf, kc)                                                     \
    do {                                                                 \
        const size_t sb = matb + (size_t)(kc0 + (kc)) * 8192;            \
        for (int i = 0; i < 4; ++i) {                                    \
            fAh[buf][i] = *(const b8v*)(Xh + sb + oA[i]);                \
            fAl[buf][i] = *(const b8v*)(Xl + sb + oA[i]);                \
            fBh[buf][i] = *(const b8v*)(Xh + sb + oB[i]);                \
            fBl[buf][i] = *(const b8v*)(Xl + sb + oB[i]);                \
        }                                                                \
    } while (0)

    LDG(0, 0);
#pragma unroll
    for (int kc = 0; kc < KCHUNK / 32; ++kc) {
        const int cb = kc & 1, nb = cb ^ 1;
        if (kc < KCHUNK / 32 - 1) LDG(nb, kc + 1);
#pragma unroll
        for (int i = 0; i < 4; ++i)
#pragma unroll
            for (int j = 0; j < 4; ++j) {
                acc[i][j] = __builtin_amdgcn_mfma_f32_16x16x32_bf16(fAh[cb][i], fBh[cb][j], acc[i][j], 0, 0, 0);
                acc[i][j] = __builtin_amdgcn_mfma_f32_16x16x32_bf16(fAh[cb][i], fBl[cb][j], acc[i][j], 0, 0, 0);
                acc[i][j] = __builtin_amdgcn_mfma_f32_16x16x32_bf16(fAl[cb][i], fBh[cb][j], acc[i][j], 0, 0, 0);
            }
    }
#undef LDG

    float* pt = part + (((size_t)pairIdx * BATCH + b) * KSPLIT + z) * 4096;
#pragma unroll
    for (int i = 0; i < 4; ++i)
#pragma unroll
        for (int j = 0; j < 4; ++j)
#pragma unroll
            for (int reg = 0; reg < 4; ++reg) {
                int row = i * 16 + q * 4 + reg;
                int col = j * 16 + r;
                pt[row * 64 + col] = acc[i][j][reg];
            }
}

// ---------------------------------------------------------------------------
// reduce partials -> a and z0 (fragment-major), mirrored via LDS transpose
// ---------------------------------------------------------------------------
__global__ __launch_bounds__(256) void k_reduce(
    const float* __restrict__ part, const float* __restrict__ sbuf,
    const float* __restrict__ trbuf,
    unsigned short* __restrict__ Ahh, unsigned short* __restrict__ All,
    unsigned short* __restrict__ Zhh, unsigned short* __restrict__ Zll) {
    const int b = blockIdx.y;
    int p = blockIdx.x, tm = 0, rem = 4;
    while (p >= rem) { p -= rem; ++tm; --rem; }
    const int tn = tm + p;

    const float* pb = part + ((size_t)blockIdx.x * BATCH + b) * KSPLIT * 4096;
    const int t = threadIdx.x;
    const int row = t >> 2, c0 = (t & 3) * 16;

    float s[16];
#pragma unroll
    for (int u = 0; u < 16; ++u) s[u] = 0.f;
    for (int sp = 0; sp < KSPLIT; ++sp) {
        const float* q4 = pb + sp * 4096 + row * 64 + c0;
#pragma unroll
        for (int u4 = 0; u4 < 4; ++u4) {
            float4 v = *(const float4*)(q4 + u4 * 4);
            s[u4 * 4 + 0] += v.x; s[u4 * 4 + 1] += v.y;
            s[u4 * 4 + 2] += v.z; s[u4 * 4 + 3] += v.w;
        }
    }

    const float invn = 1.f / (float)HW, invn2 = invn * invn;
    const float tr = trbuf[b];
    const int gi = tm * 64 + row;
    const float si = sbuf[b * C + gi];
    const size_t mb = (size_t)b * 8 * 8192;   // matrix base, 8 kc x 8192 shorts

    __shared__ unsigned short tAh[64][66], tAl[64][66], tZh[64][66], tZl[64][66];
    unsigned short vAh[16], vAl[16], vZh[16], vZl[16];
#pragma unroll
    for (int u = 0; u < 16; ++u) {
        int gj = tn * 64 + c0 + u;
        float sj = sbuf[b * C + gj];
        float a = (s[u] * invn - si * sj * invn2) / tr;
        split2(a, vAh[u], vAl[u]);
        float zv = ((gi == gj) ? 1.5f : 0.f) - 0.5f * a;
        split2(zv, vZh[u], vZl[u]);
        tAh[row][c0 + u] = vAh[u]; tAl[row][c0 + u] = vAl[u];
        tZh[row][c0 + u] = vZh[u]; tZl[row][c0 + u] = vZl[u];
    }
#pragma unroll
    for (int u4 = 0; u4 < 4; ++u4) {
        const int col0 = tn * 64 + c0 + u4 * 4;
        const size_t off = mb + (size_t)(col0 >> 5) * 8192 + (size_t)gi * 32 + (col0 & 31);
        *(ushort4*)&Ahh[off] = *(ushort4*)&vAh[u4 * 4];
        *(ushort4*)&All[off] = *(ushort4*)&vAl[u4 * 4];
        *(ushort4*)&Zhh[off] = *(ushort4*)&vZh[u4 * 4];
        *(ushort4*)&Zll[off] = *(ushort4*)&vZl[u4 * 4];
    }
    if (tm != tn) {
        __syncthreads();
        const int mr = t >> 2, mc0 = (t & 3) * 16;
        const int gim = tn * 64 + mr;
        unsigned short wAh[16], wAl[16], wZh[16], wZl[16];
#pragma unroll
        for (int u = 0; u < 16; ++u) {
            wAh[u] = tAh[mc0 + u][mr]; wAl[u] = tAl[mc0 + u][mr];
            wZh[u] = tZh[mc0 + u][mr]; wZl[u] = tZl[mc0 + u][mr];
        }
#pragma unroll
        for (int u4 = 0; u4 < 4; ++u4) {
            const int col0 = tm * 64 + mc0 + u4 * 4;
            const size_t off = mb + (size_t)(col0 >> 5) * 8192 + (size_t)gim * 32 + (col0 & 31);
            *(ushort4*)&Ahh[off] = *(ushort4*)&wAh[u4 * 4];
            *(ushort4*)&All[off] = *(ushort4*)&wAl[u4 * 4];
            *(ushort4*)&Zhh[off] = *(ushort4*)&wZh[u4 * 4];
            *(ushort4*)&Zll[off] = *(ushort4*)&wZl[u4 * 4];
        }
    }
}

// ---------------------------------------------------------------------------
// NS core: one wave, 64x64 tile, K=256, fragment-major coalesced loads,
// register dbuf. No LDS, no barriers.
// ---------------------------------------------------------------------------
__device__ __forceinline__ void wave_gemm64(
    const unsigned short* __restrict__ Ah, const unsigned short* __restrict__ Al,
    const unsigned short* __restrict__ Bh, const unsigned short* __restrict__ Bl,
    int rowA, int rowB, f4v acc[4][4]) {
    const int lane = threadIdx.x & 63;
    const int q = lane >> 4, r = lane & 15;
    int oA[4], oB[4];
#pragma unroll
    for (int i = 0; i < 4; ++i) {
        oA[i] = (rowA + i * 16 + r) * 32 + q * 8;
        oB[i] = (rowB + i * 16 + r) * 32 + q * 8;
    }
    b8v fAh[2][4], fAl[2][4], fBh[2][4], fBl[2][4];
#define LD(buf, kc)                                              \
    do {                                                         \
        const size_t sb = (size_t)(kc) * 8192;                   \
        for (int i = 0; i < 4; ++i) {                            \
            fAh[buf][i] = *(const b8v*)(Ah + sb + oA[i]);        \
            fAl[buf][i] = *(const b8v*)(Al + sb + oA[i]);        \
            fBh[buf][i] = *(const b8v*)(Bh + sb + oB[i]);        \
            fBl[buf][i] = *(const b8v*)(Bl + sb + oB[i]);        \
        }                                                        \
    } while (0)

    LD(0, 0);
#pragma unroll
    for (int kc = 0; kc < 8; ++kc) {
        const int cb = kc & 1, nb = cb ^ 1;
        if (kc < 7) LD(nb, kc + 1);
#pragma unroll
        for (int i = 0; i < 4; ++i)
#pragma unroll
            for (int j = 0; j < 4; ++j) {
                acc[i][j] = __builtin_amdgcn_mfma_f32_16x16x32_bf16(fAh[cb][i], fBh[cb][j], acc[i][j], 0, 0, 0);
                acc[i][j] = __builtin_amdgcn_mfma_f32_16x16x32_bf16(fAh[cb][i], fBl[cb][j], acc[i][j], 0, 0, 0);
                acc[i][j] = __builtin_amdgcn_mfma_f32_16x16x32_bf16(fAl[cb][i], fBh[cb][j], acc[i][j], 0, 0, 0);
            }
    }
#undef LD
}

// store one 64x64 result tile into fragment-major D (hi/lo)
__device__ __forceinline__ void store_tile_fm(
    unsigned short* __restrict__ Dh, unsigned short* __restrict__ Dl,
    int tm, int tn, const f4v acc[4][4], bool modeT) {
    const int lane = threadIdx.x & 63, q = lane >> 4, r = lane & 15;
#pragma unroll
    for (int i = 0; i < 4; ++i)
#pragma unroll
        for (int j = 0; j < 4; ++j) {
            const int gj = tn * 64 + j * 16 + r;
            const size_t cbase = (size_t)(gj >> 5) * 8192 + (gj & 31);
#pragma unroll
            for (int reg = 0; reg < 4; ++reg) {
                const int gi = tm * 64 + i * 16 + q * 4 + reg;
                float v = acc[i][j][reg];
                if (modeT) v = ((gi == gj) ? 1.5f : 0.f) - 0.5f * v;
                unsigned short h, l;
                split2(v, h, l);
                Dh[cbase + (size_t)gi * 32] = h;
                Dl[cbase + (size_t)gi * 32] = l;
            }
        }
}

// MODE 0: D = acc ; MODE 1: D = 1.5I - 0.5 acc ; MODE 2: triuvec(acc*sqrt(tr))
// XCD-pinned flat grid: batch b always lands on XCD b%8.
template <int MODE>
__global__ __launch_bounds__(64) void k_t64(
    const unsigned short* __restrict__ Ah, const unsigned short* __restrict__ Al,
    const unsigned short* __restrict__ Bh, const unsigned short* __restrict__ Bl,
    unsigned short* __restrict__ Dh, unsigned short* __restrict__ Dl,
    float* __restrict__ outF, const float* __restrict__ strbuf) {
    const int bid = blockIdx.x;
    const int x8 = bid & 7;
    const int w = bid >> 3;
    int b, tm, tn;
    if (MODE == 2) {
        b = x8 + 8 * (w / 10);
        int p = w % 10, rem = 4; tm = 0;
        while (p >= rem) { p -= rem; ++tm; --rem; }
        tn = tm + p;
    } else {
        b = x8 + 8 * (w >> 4);
        const int tile = w & 15;
        tm = tile >> 2; tn = tile & 3;
    }
    const size_t mo = (size_t)b * 8 * 8192;
    f4v acc[4][4] = {};
    wave_gemm64(Ah + mo, Al + mo, Bh + mo, Bl + mo, tm * 64, tn * 64, acc);

    if (MODE == 2) {
        const int lane = threadIdx.x & 63, q = lane >> 4, r = lane & 15;
        const float sc = strbuf[b];
#pragma unroll
        for (int i = 0; i < 4; ++i)
#pragma unroll
            for (int j = 0; j < 4; ++j) {
                const int gj = tn * 64 + j * 16 + r;
#pragma unroll
                for (int reg = 0; reg < 4; ++reg) {
                    const int gi = tm * 64 + i * 16 + q * 4 + reg;
                    if (gj >= gi)
                        outF[(size_t)b * OUTROW + (size_t)(gi * C - (gi * (gi - 1)) / 2) +
                             (gj - gi)] = acc[i][j][reg] * sc;
                }
            }
    } else {
        store_tile_fm(Dh + mo, Dl + mo, tm, tn, acc, MODE == 1);
    }
}

// fused Ynew = Y@T, Znew = T@Z ; XCD-pinned flat grid (1024 blocks)
__global__ __launch_bounds__(64) void k_yz64(
    const unsigned short* __restrict__ Yh, const unsigned short* __restrict__ Yl,
    const unsigned short* __restrict__ Th, const unsigned short* __restrict__ Tl,
    const unsigned short* __restrict__ Zh, const unsigned short* __restrict__ Zl,
    unsigned short* __restrict__ Ynh, unsigned short* __restrict__ Ynl,
    unsigned short* __restrict__ Znh, unsigned short* __restrict__ Znl) {
    const int bid = blockIdx.x;
    const int x8 = bid & 7;
    const int w = bid >> 3;                 // 0..127
    const int b = x8 + 8 * ((w >> 4) & 3);
    const int zz = w >> 6;                  // 0: Y@T, 1: T@Z
    const int tile = w & 15;
    const int tm = tile >> 2, tn = tile & 3;

    const unsigned short* Ah = zz ? Th : Yh;
    const unsigned short* Al = zz ? Tl : Yl;
    const unsigned short* Bh = zz ? Zh : Th;
    const unsigned short* Bl = zz ? Zl : Tl;
    unsigned short* Dh = zz ? Znh : Ynh;
    unsigned short* Dl = zz ? Znl : Ynl;

    const size_t mo = (size_t)b * 8 * 8192;
    f4v acc[4][4] = {};
    wave_gemm64(Ah + mo, Al + mo, Bh + mo, Bl + mo, tm * 64, tn * 64, acc);
    store_tile_fm(Dh + mo, Dl + mo, tm, tn, acc, false);
}

// ---------------------------------------------------------------------------
extern "C" void kernel_launch(void* const* d_in, const int* in_sizes, int n_in,
                              void* d_out, int out_size, void* d_ws, size_t ws_size,
                              hipStream_t stream) {
    const float* x = (const float*)d_in[0];
    float* out = (float*)d_out;

    unsigned short* W = (unsigned short*)d_ws;
    const size_t XN = (size_t)BATCH * C * HW;
    const size_t M = (size_t)BATCH * C * C;
    unsigned short* XH = W;
    unsigned short* XL = XH + XN;
    float* sbuf = (float*)(XL + XN);
    float* qbuf = sbuf + BATCH * C;
    float* trbuf = qbuf + BATCH * C;
    float* strbuf = trbuf + BATCH;
    unsigned short* P = (unsigned short*)(strbuf + BATCH);
    unsigned short* PA_h = P + 0 * M; unsigned short* PA_l = P + 1 * M;
    unsigned short* PB_h = P + 2 * M; unsigned short* PB_l = P + 3 * M;
    unsigned short* PC_h = P + 4 * M; unsigned short* PC_l = P + 5 * M;
    unsigned short* PD_h = P + 6 * M; unsigned short* PD_l = P + 7 * M;
    unsigned short* PE_h = P + 8 * M; unsigned short* PE_l = P + 9 * M;
    // fp32 partials alias PC..PE + beyond (dead until Y0 is written)
    float* part = (float*)PC_h;   // 10*32*7*4096 floats

    k_prep<<<dim3(BATCH * C), 256, 0, stream>>>(x, XH, XL, sbuf, qbuf);
    k_tr<<<dim3(BATCH), 256, 0, stream>>>(sbuf, qbuf, trbuf, strbuf);
    k_gram_split<<<dim3(10 * BATCH * KSPLIT), 64, 0, stream>>>(XH, XL, part);
    k_reduce<<<dim3(10, BATCH), 256, 0, stream>>>(part, sbuf, trbuf,
                                                  PA_h, PA_l, PB_h, PB_l);

    dim3 g512(512);
    // Y0 = a @ z0 -> PC
    k_t64<0><<<g512, 64, 0, stream>>>(PA_h, PA_l, PB_h, PB_l, PC_h, PC_l, nullptr, strbuf);
    // it0: T0 = 1.5I - 0.5 Z0@Y0 = PB@PC -> PD ; Y1 = PC@PD -> PA ; Z1 = PD@PB -> PE
    k_t64<1><<<g512, 64, 0, stream>>>(PB_h, PB_l, PC_h, PC_l, PD_h, PD_l, nullptr, strbuf);
    k_yz64<<<dim3(1024), 64, 0, stream>>>(PC_h, PC_l, PD_h, PD_l, PB_h, PB_l,
                                          PA_h, PA_l, PE_h, PE_l);
    // it1: T1 = PE@PA -> PB ; Y2 = PA@PB -> PC ; Z2 = PB@PE -> PD
    k_t64<1><<<g512, 64, 0, stream>>>(PE_h, PE_l, PA_h, PA_l, PB_h, PB_l, nullptr, strbuf);
    k_yz64<<<dim3(1024), 64, 0, stream>>>(PA_h, PA_l, PB_h, PB_l, PE_h, PE_l,
                                          PC_h, PC_l, PD_h, PD_l);
    // it2: T2 = PD@PC -> PA ; Y3 = PC@PA -> PB ; Z3 = PA@PD -> PE
    k_t64<1><<<g512, 64, 0, stream>>>(PD_h, PD_l, PC_h, PC_l, PA_h, PA_l, nullptr, strbuf);
    k_yz64<<<dim3(1024), 64, 0, stream>>>(PC_h, PC_l, PA_h, PA_l, PD_h, PD_l,
                                          PB_h, PB_l, PE_h, PE_l);
    // it3: T3 = PE@PB -> PC ; out = triuvec((PB@PC) * sqrt(tr))
    k_t64<1><<<g512, 64, 0, stream>>>(PE_h, PE_l, PB_h, PB_l, PC_h, PC_l, nullptr, strbuf);
    k_t64<2><<<dim3(320), 64, 0, stream>>>(PB_h, PB_l, PC_h, PC_l, nullptr, nullptr,
                                           out, strbuf);
}